// Round 11
// baseline (2867.225 us; speedup 1.0000x reference)
//
#include <hip/hip_runtime.h>

#define HID 128
#define NBUCK 1024         // 2^10 buckets, 128 nodes each (782 used for N=100000)
#define BSHIFT 7
#define NB 512             // chunk blocks per pipeline
#define M4 (4 * NBUCK * NB)
#define STAGE_CAP 4096     // bucket mean 2048, sigma~45; +45 sigma

typedef __attribute__((ext_vector_type(8))) short bf16x8;
typedef __attribute__((ext_vector_type(4))) float f32x4;

__device__ __forceinline__ unsigned short f2bf(float f) {   // RNE
    union { float f; unsigned u; } v; v.f = f;
    unsigned r = v.u + 0x7fff + ((v.u >> 16) & 1);
    return (unsigned short)(r >> 16);
}
__device__ __forceinline__ float bf2f(unsigned short b) {
    union { float f; unsigned u; } v; v.u = ((unsigned)b) << 16;
    return v.f;
}

// async global->LDS, 16B per lane (global_load_lds_dwordx4)
__device__ __forceinline__ void gload_lds16(const void* g, void* l) {
    __builtin_amdgcn_global_load_lds(
        (const __attribute__((address_space(1))) void*)g,
        (__attribute__((address_space(3))) void*)l, 16, 0, 0);
}

// ---------------------------------------------------------------- P1: all 4 pipes, per-(bucket, block) counts
__global__ __launch_bounds__(256) void bucket_count_all(
    const int* __restrict__ k0, const int* __restrict__ k1,
    const int* __restrict__ k2, const int* __restrict__ k3,
    int* __restrict__ counts, int E, int chunk) {
    __shared__ int h[4][NBUCK];   // 16 KB
    int tid = threadIdx.x;
    #pragma unroll
    for (int j = 0; j < 16; ++j) ((int*)h)[tid + j * 256] = 0;
    __syncthreads();
    int base = blockIdx.x * chunk;
    int end = min(base + chunk, E);
    const int* keys[4] = {k0, k1, k2, k3};
    #pragma unroll
    for (int p = 0; p < 4; ++p) {
        const int* kp = keys[p];
        for (int i = base + tid; i < end; i += 256)
            atomicAdd(&h[p][kp[i] >> BSHIFT], 1);
    }
    __syncthreads();
    #pragma unroll
    for (int p = 0; p < 4; ++p)
        #pragma unroll
        for (int j = 0; j < 4; ++j) {
            int bkt = tid + j * 256;
            counts[((p << 10) + bkt) * NB + blockIdx.x] = h[p][bkt];
        }
}

// ---------------------------------------------------------------- scan (3 kernels)
__global__ __launch_bounds__(256) void scan_a(int* __restrict__ data, int* __restrict__ partials, int m) {
    __shared__ int sdata[256];
    int base = blockIdx.x * 1024;
    int tid = threadIdx.x;
    int v[4]; int s = 0;
    #pragma unroll
    for (int i = 0; i < 4; ++i) { int idx = base + tid * 4 + i; v[i] = (idx < m) ? data[idx] : 0; s += v[i]; }
    sdata[tid] = s; __syncthreads();
    for (int off = 1; off < 256; off <<= 1) {
        int t = (tid >= off) ? sdata[tid - off] : 0; __syncthreads();
        sdata[tid] += t; __syncthreads();
    }
    int excl = sdata[tid] - s;
    if (tid == 255) partials[blockIdx.x] = sdata[255];
    int run = excl;
    #pragma unroll
    for (int i = 0; i < 4; ++i) { int idx = base + tid * 4 + i; if (idx < m) data[idx] = run; run += v[i]; }
}

__global__ __launch_bounds__(1024) void scan_b(int* __restrict__ partials, int nb) {
    __shared__ int sdata[1024];
    int tid = threadIdx.x;
    int i0 = 2 * tid, i1 = 2 * tid + 1;
    int v0 = (i0 < nb) ? partials[i0] : 0;
    int v1 = (i1 < nb) ? partials[i1] : 0;
    int s = v0 + v1;
    sdata[tid] = s; __syncthreads();
    for (int off = 1; off < 1024; off <<= 1) {
        int t = (tid >= off) ? sdata[tid - off] : 0; __syncthreads();
        sdata[tid] += t; __syncthreads();
    }
    int excl = sdata[tid] - s;
    if (i0 < nb) partials[i0] = excl;
    if (i1 < nb) partials[i1] = excl + v0;
}

__global__ __launch_bounds__(256) void scan_c(int* __restrict__ data, const int* __restrict__ partials, int m) {
    int i = blockIdx.x * 256 + threadIdx.x;
    if (i < m) data[i] += partials[i >> 10];
}

// ---------------------------------------------------------------- P3: all 4 pipes, scatter into buckets
__global__ __launch_bounds__(256) void bucket_scatter_all(
    const int* __restrict__ k0, const int* __restrict__ k1,
    const int* __restrict__ k2, const int* __restrict__ k3,
    const int* __restrict__ pay0, const int* __restrict__ pay1,
    const int* __restrict__ scanned, unsigned* __restrict__ bucketed,
    int E, int chunk) {
    __shared__ unsigned cur[4][NBUCK];   // 16 KB
    int tid = threadIdx.x;
    int blk = blockIdx.x;
    #pragma unroll
    for (int p = 0; p < 4; ++p)
        #pragma unroll
        for (int j = 0; j < 4; ++j) {
            int bkt = tid + j * 256;
            cur[p][bkt] = (unsigned)scanned[((p << 10) + bkt) * NB + blk];
        }
    __syncthreads();
    int base = blk * chunk;
    int end = min(base + chunk, E);
    const int* keys[4] = {k0, k1, k2, k3};
    const int* pays[4] = {pay0, pay1, nullptr, nullptr};
    #pragma unroll
    for (int p = 0; p < 4; ++p) {
        const int* kp = keys[p];
        const int* pp = pays[p];
        for (int i = base + tid; i < end; i += 256) {
            int k = kp[i];
            int b = k >> BSHIFT;
            unsigned pay = pp ? (unsigned)pp[i] : 0u;
            unsigned pos = atomicAdd(&cur[p][b], 1u);
            bucketed[pos] = ((unsigned)(k & 127) << 17) | pay;
        }
    }
}

// ---------------------------------------------------------------- P4: per bucket: degrees; dst pipes also src-sort (512-src bins) in place
__global__ __launch_bounds__(256) void bucket_finalize(
    unsigned* __restrict__ bucketed, const int* __restrict__ scanned,
    int* __restrict__ din0, int* __restrict__ din1,
    int* __restrict__ dout0, int* __restrict__ dout1, int n, int E) {
    __shared__ unsigned stage[STAGE_CAP];    // 16 KB
    __shared__ unsigned stage2[STAGE_CAP];   // 16 KB
    __shared__ int cnt[128];
    __shared__ int sd[256];
    __shared__ int h2[256];
    __shared__ int bincur[256];
    int tid = threadIdx.x;
    int g = blockIdx.x;            // 0..4095
    int p = g >> 10;
    int b = g & 1023;
    int start = scanned[g * NB];
    int end = (g == 4 * NBUCK - 1) ? 4 * E : scanned[(g + 1) * NB];
    if (end - start > STAGE_CAP) end = start + STAGE_CAP;   // unreachable safety clamp
    int len = end - start;
    int node0 = b << BSHIFT;

    if (tid < 128) cnt[tid] = 0;
    h2[tid] = 0;
    __syncthreads();
    if (p < 2) {
        for (int i = tid; i < len; i += 256) {
            unsigned v = bucketed[start + i];
            stage[i] = v;
            atomicAdd(&cnt[v >> 17], 1);
            atomicAdd(&h2[(v & 0x1FFFFu) >> 9], 1);
        }
    } else {
        for (int i = tid; i < len; i += 256)
            atomicAdd(&cnt[bucketed[start + i] >> 17], 1);
    }
    __syncthreads();

    if (p >= 2) {                   // src-keyed: out-degrees only
        int* dout = (p == 2) ? dout0 : dout1;
        int node = node0 + tid;
        if (tid < 128 && node < n) dout[node] = cnt[tid];
        return;
    }

    // dst-keyed: in-degrees
    {
        int* din = (p == 0) ? din0 : din1;
        int node = node0 + tid;
        if (tid < 128 && node < n) din[node] = cnt[tid];
    }

    // scan h2 -> bin cursors
    int hv = h2[tid];
    sd[tid] = hv; __syncthreads();
    for (int off = 1; off < 256; off <<= 1) {
        int t = (tid >= off) ? sd[tid - off] : 0; __syncthreads();
        sd[tid] += t; __syncthreads();
    }
    bincur[tid] = sd[tid] - hv;
    __syncthreads();

    // scatter by src-high bin (approximate src sort, 512-src granularity)
    for (int i = tid; i < len; i += 256) {
        unsigned v = stage[i];
        int pos = atomicAdd(&bincur[(v & 0x1FFFFu) >> 9], 1);
        stage2[pos] = v;
    }
    __syncthreads();

    // write back sorted edges in place (coalesced)
    for (int i = tid; i < len; i += 256)
        bucketed[start + i] = stage2[i];
}

// ---------------------------------------------------------------- swizzled B-fragment index for mfma_f32_16x16x32_bf16
__device__ __forceinline__ size_t bswz_idx(int k, int col) {
    int s = k >> 5, lh = (k >> 3) & 3, j = k & 7;
    int c = col >> 4, lc = col & 15;
    return ((((size_t)s * 8 + c) * 64 + (lh * 16 + lc)) * 8 + j);
}

// ---------------------------------------------------------------- weight_fuse: M = We@W1 -> swizzled split bf16; cv = be@W1
__global__ __launch_bounds__(256) void weight_fuse(
    const float* __restrict__ We, const float* __restrict__ be,
    const float* __restrict__ W1,
    unsigned short* __restrict__ B1h, unsigned short* __restrict__ B1l,
    float* __restrict__ cv) {
    __shared__ float w1[128][128];
    int tid = threadIdx.x;
    #pragma unroll
    for (int it = 0; it < 16; ++it) {
        int s = tid + it * 256;
        int r = s >> 5, c4 = (s & 31) << 2;
        *(float4*)&w1[r][c4] = *(const float4*)&W1[r * 128 + c4];
    }
    __syncthreads();
    int j = tid & 127;
    int half = tid >> 7;
    if (blockIdx.x == 128) {
        if (half) return;
        float sum = 0.f;
        for (int k = 0; k < 128; ++k) sum += be[k] * w1[k][j];
        cv[j] = sum;
        return;
    }
    int i = blockIdx.x * 2 + half;
    const float* arow = &We[i * 128];
    float sum = 0.f;
    for (int k = 0; k < 128; ++k) sum += arow[k] * w1[k][j];
    unsigned short h = f2bf(sum);
    unsigned short l = f2bf(sum - bf2f(h));
    size_t o = bswz_idx(i, j);
    B1h[o] = h; B1l[o] = l;
}

__global__ __launch_bounds__(256) void swizzle_split(
    const float* __restrict__ W, unsigned short* __restrict__ Bh,
    unsigned short* __restrict__ Bl, int K) {
    int idx = blockIdx.x * 256 + threadIdx.x;
    if (idx >= K * 128) return;
    int k = idx >> 7, col = idx & 127;
    float v = W[idx];
    unsigned short h = f2bf(v);
    unsigned short l = f2bf(v - bf2f(h));
    size_t o = bswz_idx(k, col);
    Bh[o] = h; Bl[o] = l;
}

// ---------------------------------------------------------------- MFMA GEMM, LDS-staged B, double-buffered, 8-wave blocks
template <int K, bool AFP32>
__global__ __launch_bounds__(512) void gemm_lds(
    const void* __restrict__ X_,
    const unsigned short* __restrict__ Bh, const unsigned short* __restrict__ Bl,
    const float* __restrict__ cvec, const int* __restrict__ degs,
    unsigned short* __restrict__ T, int n) {
    constexpr int NS = K / 32;
    __shared__ __align__(16) char smem[2 * 16384];
    const int tid = threadIdx.x;
    const int wave = tid >> 6;
    const int lane = tid & 63;
    const int lr = lane & 15;
    const int lk = lane >> 4;
    const int row0 = blockIdx.x * 128 + wave * 16;
    const int grow = row0 + lr;
    const bool vr = grow < n;

    f32x4 acc[8];
    #pragma unroll
    for (int c = 0; c < 8; ++c) acc[c] = (f32x4)0.f;

    auto stage_slab = [&](int s, char* dst) {
        #pragma unroll
        for (int it = 0; it < 2; ++it) {
            int u = tid + it * 512;
            int f = u >> 6;
            int c = f >> 1, plane = f & 1;
            const unsigned short* srcArr = plane ? Bl : Bh;
            const char* g = (const char*)srcArr +
                ((size_t)(s * 512 + c * 64 + (u & 63)) * 16);
            gload_lds16(g, dst + u * 16);
        }
    };

    stage_slab(0, smem);

    const float* pxf = AFP32 ? (const float*)X_ + (size_t)grow * K + lk * 8 : nullptr;
    const unsigned short* pxb = AFP32 ? nullptr : (const unsigned short*)X_ + (size_t)grow * K + lk * 8;
    float4 a0 = make_float4(0.f, 0.f, 0.f, 0.f), a1 = a0;
    bf16x8 ab = (bf16x8)0;
    if (AFP32) {
        if (vr) { a0 = *(const float4*)pxf; a1 = *(const float4*)(pxf + 4); }
    } else {
        if (vr) ab = *(const bf16x8*)pxb;
    }

    #pragma unroll
    for (int s = 0; s < NS; ++s) {
        __syncthreads();
        if (s + 1 < NS) stage_slab(s + 1, smem + ((s + 1) & 1) * 16384);

        float4 n0 = make_float4(0.f, 0.f, 0.f, 0.f), n1 = n0;
        bf16x8 nb = (bf16x8)0;
        if (s + 1 < NS && vr) {
            if (AFP32) {
                n0 = *(const float4*)(pxf + (s + 1) * 32);
                n1 = *(const float4*)(pxf + (s + 1) * 32 + 4);
            } else {
                nb = *(const bf16x8*)(pxb + (s + 1) * 32);
            }
        }

        bf16x8 ah, al;
        if (AFP32) {
            float av[8] = {a0.x, a0.y, a0.z, a0.w, a1.x, a1.y, a1.z, a1.w};
            #pragma unroll
            for (int j = 0; j < 8; ++j) {
                unsigned short h = f2bf(av[j]);
                ah[j] = (short)h;
                al[j] = (short)f2bf(av[j] - bf2f(h));
            }
        } else {
            ah = ab;
        }

        const char* base = smem + (s & 1) * 16384 + lane * 16;
        #pragma unroll
        for (int c = 0; c < 8; ++c) {
            bf16x8 bh = *(const bf16x8*)(base + (c * 2) * 1024);
            bf16x8 bl = *(const bf16x8*)(base + (c * 2 + 1) * 1024);
            acc[c] = __builtin_amdgcn_mfma_f32_16x16x32_bf16(ah, bh, acc[c], 0, 0, 0);
            acc[c] = __builtin_amdgcn_mfma_f32_16x16x32_bf16(ah, bl, acc[c], 0, 0, 0);
            if (AFP32)
                acc[c] = __builtin_amdgcn_mfma_f32_16x16x32_bf16(al, bh, acc[c], 0, 0, 0);
        }
        a0 = n0; a1 = n1; ab = nb;
    }

    #pragma unroll
    for (int r = 0; r < 4; ++r) {
        int orow = row0 + lk * 4 + r;
        if (orow >= n) continue;
        float norm = rsqrtf(fmaxf((float)degs[orow], 1.0f));
        #pragma unroll
        for (int c = 0; c < 8; ++c) {
            float v = acc[c][r];
            if (cvec) v += cvec[c * 16 + lr];
            T[(size_t)orow * 128 + c * 16 + lr] = f2bf(v * norm);
        }
    }
}

// ---------------------------------------------------------------- aggregate (blocked SpMM):
// block = one 128-node dst bucket, fp32 accumulator tile in LDS; edges (src-sorted
// in bucketed) walked in order by 4 waves -> concurrent src window stays L2-hot.
template <bool OUT_BF16>
__global__ __launch_bounds__(256) void aggregate_bucket(
    const unsigned short* __restrict__ T, const unsigned* __restrict__ bucketed,
    const int* __restrict__ scanned, const int* __restrict__ din,
    const float* __restrict__ bias, void* __restrict__ out_,
    int pipe, int n, int E) {
    __shared__ float acc[128][129];   // +1 pad: atomics & reads 2-way banks (free)
    const int tid = threadIdx.x;
    const int wave = tid >> 6;
    const int lane = tid & 63;
    const int b = blockIdx.x;
    const int g = (pipe << 10) + b;
    int start = scanned[g * NB];
    int end = (g == 4 * NBUCK - 1) ? 4 * E : scanned[(g + 1) * NB];
    if (end - start > STAGE_CAP) end = start + STAGE_CAP;
    const int node0 = b << BSHIFT;

    for (int j = tid; j < 128 * 129; j += 256) ((float*)acc)[j] = 0.f;
    __syncthreads();

    // 8 edges per wave iteration (independent gathers), waves interleaved for a tight src window
    for (int i = start + wave * 8; i < end; i += 32) {
        int m = end - i; if (m > 8) m = 8;
        unsigned w[8]; unsigned gv[8];
        #pragma unroll
        for (int j = 0; j < 8; ++j) {
            int idx = i + (j < m ? j : 0);
            w[j] = bucketed[idx];
        }
        #pragma unroll
        for (int j = 0; j < 8; ++j) {
            int src = (int)(w[j] & 0x1FFFFu);
            gv[j] = *(const unsigned*)&T[(size_t)src * 128 + lane * 2];
        }
        #pragma unroll
        for (int j = 0; j < 8; ++j) {
            if (j < m) {
                int dl = (int)(w[j] >> 17);
                float f0 = __uint_as_float(gv[j] << 16);
                float f1 = __uint_as_float(gv[j] & 0xffff0000u);
                atomicAdd(&acc[dl][lane * 2], f0);
                atomicAdd(&acc[dl][lane * 2 + 1], f1);
            }
        }
    }
    __syncthreads();

    // epilogue: thread t -> node t>>1, feature half (t&1)*64
    const int dl = tid >> 1;
    const int fh = (tid & 1) * 64;
    const int node = node0 + dl;
    if (node >= n) return;
    float norm = rsqrtf(fmaxf((float)din[node], 1.0f));
    if (OUT_BF16) {
        unsigned short* orow = (unsigned short*)out_ + (size_t)node * 128 + fh;
        #pragma unroll
        for (int j = 0; j < 64; j += 8) {
            unsigned pk[4];
            #pragma unroll
            for (int k = 0; k < 4; ++k) {
                float2 c = *(const float2*)&acc[dl][fh + j + 2 * k];
                float2 bv = *(const float2*)&bias[fh + j + 2 * k];
                float o0 = fmaxf(c.x * norm + bv.x, 0.f);
                float o1 = fmaxf(c.y * norm + bv.y, 0.f);
                pk[k] = (unsigned)f2bf(o0) | ((unsigned)f2bf(o1) << 16);
            }
            *(uint4*)&orow[j] = make_uint4(pk[0], pk[1], pk[2], pk[3]);
        }
    } else {
        float* orow = (float*)out_ + (size_t)node * 128 + fh;
        #pragma unroll
        for (int j = 0; j < 64; j += 4) {
            float2 c0 = *(const float2*)&acc[dl][fh + j];
            float2 c1 = *(const float2*)&acc[dl][fh + j + 2];
            float4 bv = *(const float4*)&bias[fh + j];
            float4 o;
            o.x = fmaxf(c0.x * norm + bv.x, 0.f);
            o.y = fmaxf(c0.y * norm + bv.y, 0.f);
            o.z = fmaxf(c1.x * norm + bv.z, 0.f);
            o.w = fmaxf(c1.y * norm + bv.w, 0.f);
            *(float4*)&orow[j] = o;
        }
    }
}

// ---------------------------------------------------------------- launch
extern "C" void kernel_launch(void* const* d_in, const int* in_sizes, int n_in,
                              void* d_out, int out_size, void* d_ws, size_t ws_size,
                              hipStream_t stream) {
    const float* x   = (const float*)d_in[0];
    const float* We  = (const float*)d_in[1];
    const float* be  = (const float*)d_in[2];
    const float* W1  = (const float*)d_in[3];
    const float* b1  = (const float*)d_in[4];
    const float* W2  = (const float*)d_in[5];
    const float* b2  = (const float*)d_in[6];
    const int* src0  = (const int*)d_in[7];
    const int* dst0  = (const int*)d_in[8];
    const int* src1  = (const int*)d_in[9];
    const int* dst1  = (const int*)d_in[10];
    float* out = (float*)d_out;

    const int n = in_sizes[0] / 256;   // 100000
    const int E = in_sizes[7];         // 1600000
    const int chunk = (E + NB - 1) / NB;

    char* p = (char*)d_ws;
    auto carve = [&](size_t bytes) -> void* {
        void* r = (void*)p;
        p += (bytes + 511) & ~(size_t)511;
        return r;
    };
    unsigned short* t        = (unsigned short*)carve((size_t)n * HID * 2);  // [n][128] bf16
    unsigned short* h1       = (unsigned short*)carve((size_t)n * HID * 2);  // [n][128] bf16
    unsigned*       bucketed = (unsigned*)carve((size_t)4 * E * 4);
    int*            counts   = (int*)carve((size_t)M4 * 4);                  // 8 MB
    int*            partials = (int*)carve(2048 * 4);
    int*            din0     = (int*)carve((size_t)n * 4);
    int*            din1     = (int*)carve((size_t)n * 4);
    int*            dout0    = (int*)carve((size_t)n * 4);
    int*            dout1    = (int*)carve((size_t)n * 4);
    unsigned short* B1h      = (unsigned short*)carve(256 * HID * 2);
    unsigned short* B1l      = (unsigned short*)carve(256 * HID * 2);
    unsigned short* B2h      = (unsigned short*)carve(128 * HID * 2);
    unsigned short* B2l      = (unsigned short*)carve(128 * HID * 2);
    float*          cv       = (float*)carve(HID * 4);

    const int gGemm  = (n + 127) / 128;          // 782 blocks, 8 waves
    const int gBuck  = (n + 127) / 128;          // 782 used dst buckets
    const int gScanA = M4 / 1024;                // 2048
    const int gScanC = M4 / 256;                 // 8192

    // --- graph build (zero global atomics) ---
    bucket_count_all<<<NB, 256, 0, stream>>>(dst0, dst1, src0, src1, counts, E, chunk);
    scan_a<<<gScanA, 256, 0, stream>>>(counts, partials, M4);
    scan_b<<<1, 1024, 0, stream>>>(partials, gScanA);
    scan_c<<<gScanC, 256, 0, stream>>>(counts, partials, M4);
    bucket_scatter_all<<<NB, 256, 0, stream>>>(dst0, dst1, src0, src1, src0, src1,
                                               counts, bucketed, E, chunk);
    bucket_finalize<<<4 * NBUCK, 256, 0, stream>>>(bucketed, counts, din0, din1, dout0, dout1, n, E);

    // --- weights ---
    weight_fuse<<<129, 256, 0, stream>>>(We, be, W1, B1h, B1l, cv);
    swizzle_split<<<(128 * 128 + 255) / 256, 256, 0, stream>>>(W2, B2h, B2l, 128);

    // --- network ---
    gemm_lds<256, true><<<gGemm, 512, 0, stream>>>((const void*)x, B1h, B1l, cv, dout0, t, n);
    aggregate_bucket<true><<<gBuck, 256, 0, stream>>>(t, bucketed, counts, din0, b1, (void*)h1, 0, n, E);
    gemm_lds<128, false><<<gGemm, 512, 0, stream>>>((const void*)h1, B2h, B2l, nullptr, dout1, t, n);
    aggregate_bucket<false><<<gBuck, 256, 0, stream>>>(t, bucketed, counts, din1, b2, (void*)out, 1, n, E);
}

// Round 12
// 306.674 us; speedup vs baseline: 9.3494x; 9.3494x over previous
//
#include <hip/hip_runtime.h>

#define HID 128
#define NBUCK 512          // 2^9 buckets, 256 nodes each
#define BSHIFT 8
#define NB 512             // chunk blocks per pipeline
#define M4 (4 * NBUCK * NB)
#define STAGE_CAP 8192     // real edges per bucket: mean 4096, +64 sigma
#define PCAP 7168          // padded csr slots per bucket: mean 5888, +10 sigma

typedef __attribute__((ext_vector_type(8))) short bf16x8;
typedef __attribute__((ext_vector_type(4))) float f32x4;

__device__ __forceinline__ unsigned short f2bf(float f) {   // RNE
    union { float f; unsigned u; } v; v.f = f;
    unsigned r = v.u + 0x7fff + ((v.u >> 16) & 1);
    return (unsigned short)(r >> 16);
}
__device__ __forceinline__ float bf2f(unsigned short b) {
    union { float f; unsigned u; } v; v.u = ((unsigned)b) << 16;
    return v.f;
}

// async global->LDS, 16B per lane (global_load_lds_dwordx4)
__device__ __forceinline__ void gload_lds16(const void* g, void* l) {
    __builtin_amdgcn_global_load_lds(
        (const __attribute__((address_space(1))) void*)g,
        (__attribute__((address_space(3))) void*)l, 16, 0, 0);
}

// ---------------------------------------------------------------- P1: all 4 pipes, per-(bucket, block) counts
__global__ __launch_bounds__(256) void bucket_count_all(
    const int* __restrict__ k0, const int* __restrict__ k1,
    const int* __restrict__ k2, const int* __restrict__ k3,
    int* __restrict__ counts, int E, int chunk) {
    __shared__ int h[4][NBUCK];
    int tid = threadIdx.x;
    #pragma unroll
    for (int j = 0; j < 8; ++j) ((int*)h)[tid + j * 256] = 0;
    __syncthreads();
    int base = blockIdx.x * chunk;
    int end = min(base + chunk, E);
    const int* keys[4] = {k0, k1, k2, k3};
    #pragma unroll
    for (int p = 0; p < 4; ++p) {
        const int* kp = keys[p];
        for (int i = base + tid; i < end; i += 256)
            atomicAdd(&h[p][kp[i] >> BSHIFT], 1);
    }
    __syncthreads();
    #pragma unroll
    for (int p = 0; p < 4; ++p) {
        counts[((p << 9) + tid) * NB + blockIdx.x] = h[p][tid];
        counts[((p << 9) + tid + 256) * NB + blockIdx.x] = h[p][tid + 256];
    }
}

// ---------------------------------------------------------------- scan (3 kernels)
__global__ __launch_bounds__(256) void scan_a(int* __restrict__ data, int* __restrict__ partials, int m) {
    __shared__ int sdata[256];
    int base = blockIdx.x * 1024;
    int tid = threadIdx.x;
    int v[4]; int s = 0;
    #pragma unroll
    for (int i = 0; i < 4; ++i) { int idx = base + tid * 4 + i; v[i] = (idx < m) ? data[idx] : 0; s += v[i]; }
    sdata[tid] = s; __syncthreads();
    for (int off = 1; off < 256; off <<= 1) {
        int t = (tid >= off) ? sdata[tid - off] : 0; __syncthreads();
        sdata[tid] += t; __syncthreads();
    }
    int excl = sdata[tid] - s;
    if (tid == 255) partials[blockIdx.x] = sdata[255];
    int run = excl;
    #pragma unroll
    for (int i = 0; i < 4; ++i) { int idx = base + tid * 4 + i; if (idx < m) data[idx] = run; run += v[i]; }
}

__global__ __launch_bounds__(1024) void scan_b(int* __restrict__ partials, int nb) {
    __shared__ int sdata[1024];
    int tid = threadIdx.x;
    int v = (tid < nb) ? partials[tid] : 0;
    sdata[tid] = v; __syncthreads();
    for (int off = 1; off < 1024; off <<= 1) {
        int t = (tid >= off) ? sdata[tid - off] : 0; __syncthreads();
        sdata[tid] += t; __syncthreads();
    }
    if (tid < nb) partials[tid] = sdata[tid] - v;
}

__global__ __launch_bounds__(256) void scan_c(int* __restrict__ data, const int* __restrict__ partials, int m) {
    int i = blockIdx.x * 256 + threadIdx.x;
    if (i < m) data[i] += partials[i >> 10];
}

// ---------------------------------------------------------------- P3: all 4 pipes, scatter into buckets
__global__ __launch_bounds__(256) void bucket_scatter_all(
    const int* __restrict__ k0, const int* __restrict__ k1,
    const int* __restrict__ k2, const int* __restrict__ k3,
    const int* __restrict__ pay0, const int* __restrict__ pay1,
    const int* __restrict__ scanned, unsigned* __restrict__ bucketed,
    int E, int chunk) {
    __shared__ unsigned cur[4][NBUCK];
    int tid = threadIdx.x;
    int blk = blockIdx.x;
    #pragma unroll
    for (int p = 0; p < 4; ++p) {
        cur[p][tid]       = (unsigned)scanned[((p << 9) + tid) * NB + blk];
        cur[p][tid + 256] = (unsigned)scanned[((p << 9) + tid + 256) * NB + blk];
    }
    __syncthreads();
    int base = blk * chunk;
    int end = min(base + chunk, E);
    const int* keys[4] = {k0, k1, k2, k3};
    const int* pays[4] = {pay0, pay1, nullptr, nullptr};
    #pragma unroll
    for (int p = 0; p < 4; ++p) {
        const int* kp = keys[p];
        const int* pp = pays[p];
        for (int i = base + tid; i < end; i += 256) {
            int k = kp[i];
            int b = k >> BSHIFT;
            unsigned pay = pp ? (unsigned)pp[i] : 0u;
            unsigned pos = atomicAdd(&cur[p][b], 1u);
            bucketed[pos] = ((unsigned)(k & 255) << 17) | pay;
        }
    }
}

// ---------------------------------------------------------------- P4: per bucket: degrees; dst pipes write PADDED csr (pad -> zero row n)
__global__ __launch_bounds__(256) void bucket_finalize(
    const unsigned* __restrict__ bucketed, const int* __restrict__ scanned,
    int* __restrict__ prow0, int* __restrict__ prow1,
    int* __restrict__ din0, int* __restrict__ din1,
    int* __restrict__ dout0, int* __restrict__ dout1,
    int* __restrict__ csr0, int* __restrict__ csr1, int n, int E) {
    __shared__ unsigned stage[STAGE_CAP];
    __shared__ int cnt[256];
    __shared__ int sd[256];
    __shared__ int pexcl[256];
    __shared__ int cur[256];
    int tid = threadIdx.x;
    int g = blockIdx.x;
    int p = g >> 9;
    int b = g & 511;
    int start = scanned[g * NB];
    int end = (g == 4 * NBUCK - 1) ? 4 * E : scanned[(g + 1) * NB];
    if (end - start > STAGE_CAP) end = start + STAGE_CAP;
    int len = end - start;
    int node0 = b << BSHIFT;

    cnt[tid] = 0;
    __syncthreads();
    if (p < 2) {
        for (int i = tid; i < len; i += 256) {
            unsigned v = bucketed[start + i];
            stage[i] = v;
            atomicAdd(&cnt[v >> 17], 1);
        }
    } else {
        for (int i = tid; i < len; i += 256)
            atomicAdd(&cnt[bucketed[start + i] >> 17], 1);
    }
    __syncthreads();

    if (p >= 2) {                   // src-keyed: out-degrees only
        int* dout = (p == 2) ? dout0 : dout1;
        int node = node0 + tid;
        if (node < n) dout[node] = cnt[tid];
        return;
    }

    // dst-keyed: padded exclusive scan of ceil(cnt/16)*16
    int c = cnt[tid];
    int pc = (c + 15) & ~15;
    sd[tid] = pc;
    __syncthreads();
    for (int off = 1; off < 256; off <<= 1) {
        int t = (tid >= off) ? sd[tid - off] : 0; __syncthreads();
        sd[tid] += t; __syncthreads();
    }
    pexcl[tid] = sd[tid] - pc;
    cur[tid] = 0;
    __syncthreads();
    int ptot = sd[255];
    if (ptot > PCAP) ptot = PCAP;   // unreachable (+10 sigma)

    int* csr  = (p == 0) ? csr0  : csr1;
    int* prow = (p == 0) ? prow0 : prow1;
    int* din  = (p == 0) ? din0  : din1;
    int node = node0 + tid;
    if (node < n) { prow[node] = b * PCAP + pexcl[tid]; din[node] = c; }

    const int base = b * PCAP;
    for (int j = tid; j < ptot; j += 256) csr[base + j] = n;   // pad = zero row
    __syncthreads();
    for (int i = tid; i < len; i += 256) {
        unsigned w = stage[i];
        int nl = (int)(w >> 17);
        int pos = base + pexcl[nl] + atomicAdd(&cur[nl], 1);
        csr[pos] = (int)(w & 0x1FFFFu);
    }
}

// ---------------------------------------------------------------- swizzled B-fragment index for mfma_f32_16x16x32_bf16
__device__ __forceinline__ size_t bswz_idx(int k, int col) {
    int s = k >> 5, lh = (k >> 3) & 3, j = k & 7;
    int c = col >> 4, lc = col & 15;
    return ((((size_t)s * 8 + c) * 64 + (lh * 16 + lc)) * 8 + j);
}

// ---------------------------------------------------------------- weight_fuse: M = We@W1 -> swizzled split bf16; cv = be@W1
__global__ __launch_bounds__(256) void weight_fuse(
    const float* __restrict__ We, const float* __restrict__ be,
    const float* __restrict__ W1,
    unsigned short* __restrict__ B1h, unsigned short* __restrict__ B1l,
    float* __restrict__ cv) {
    __shared__ float w1[128][128];
    int tid = threadIdx.x;
    #pragma unroll
    for (int it = 0; it < 16; ++it) {
        int s = tid + it * 256;
        int r = s >> 5, c4 = (s & 31) << 2;
        *(float4*)&w1[r][c4] = *(const float4*)&W1[r * 128 + c4];
    }
    __syncthreads();
    int j = tid & 127;
    int half = tid >> 7;
    if (blockIdx.x == 128) {
        if (half) return;
        float sum = 0.f;
        for (int k = 0; k < 128; ++k) sum += be[k] * w1[k][j];
        cv[j] = sum;
        return;
    }
    int i = blockIdx.x * 2 + half;
    const float* arow = &We[i * 128];
    float sum = 0.f;
    for (int k = 0; k < 128; ++k) sum += arow[k] * w1[k][j];
    unsigned short h = f2bf(sum);
    unsigned short l = f2bf(sum - bf2f(h));
    size_t o = bswz_idx(i, j);
    B1h[o] = h; B1l[o] = l;
}

__global__ __launch_bounds__(256) void swizzle_split(
    const float* __restrict__ W, unsigned short* __restrict__ Bh,
    unsigned short* __restrict__ Bl, int K) {
    int idx = blockIdx.x * 256 + threadIdx.x;
    if (idx >= K * 128) return;
    int k = idx >> 7, col = idx & 127;
    float v = W[idx];
    unsigned short h = f2bf(v);
    unsigned short l = f2bf(v - bf2f(h));
    size_t o = bswz_idx(k, col);
    Bh[o] = h; Bl[o] = l;
}

// ---------------------------------------------------------------- MFMA GEMM, LDS-staged B, double-buffered, 8-wave blocks
template <int K, bool AFP32>
__global__ __launch_bounds__(512) void gemm_lds(
    const void* __restrict__ X_,
    const unsigned short* __restrict__ Bh, const unsigned short* __restrict__ Bl,
    const float* __restrict__ cvec, const int* __restrict__ degs,
    unsigned short* __restrict__ T, int n) {
    constexpr int NS = K / 32;
    __shared__ __align__(16) char smem[2 * 16384];
    const int tid = threadIdx.x;
    const int wave = tid >> 6;
    const int lane = tid & 63;
    const int lr = lane & 15;
    const int lk = lane >> 4;
    const int row0 = blockIdx.x * 128 + wave * 16;
    const int grow = row0 + lr;
    const bool vr = grow < n;

    f32x4 acc[8];
    #pragma unroll
    for (int c = 0; c < 8; ++c) acc[c] = (f32x4)0.f;

    auto stage_slab = [&](int s, char* dst) {
        #pragma unroll
        for (int it = 0; it < 2; ++it) {
            int u = tid + it * 512;
            int f = u >> 6;
            int c = f >> 1, plane = f & 1;
            const unsigned short* srcArr = plane ? Bl : Bh;
            const char* g = (const char*)srcArr +
                ((size_t)(s * 512 + c * 64 + (u & 63)) * 16);
            gload_lds16(g, dst + u * 16);
        }
    };

    stage_slab(0, smem);

    const float* pxf = AFP32 ? (const float*)X_ + (size_t)grow * K + lk * 8 : nullptr;
    const unsigned short* pxb = AFP32 ? nullptr : (const unsigned short*)X_ + (size_t)grow * K + lk * 8;
    float4 a0 = make_float4(0.f, 0.f, 0.f, 0.f), a1 = a0;
    bf16x8 ab = (bf16x8)0;
    if (AFP32) {
        if (vr) { a0 = *(const float4*)pxf; a1 = *(const float4*)(pxf + 4); }
    } else {
        if (vr) ab = *(const bf16x8*)pxb;
    }

    #pragma unroll
    for (int s = 0; s < NS; ++s) {
        __syncthreads();
        if (s + 1 < NS) stage_slab(s + 1, smem + ((s + 1) & 1) * 16384);

        float4 n0 = make_float4(0.f, 0.f, 0.f, 0.f), n1 = n0;
        bf16x8 nb = (bf16x8)0;
        if (s + 1 < NS && vr) {
            if (AFP32) {
                n0 = *(const float4*)(pxf + (s + 1) * 32);
                n1 = *(const float4*)(pxf + (s + 1) * 32 + 4);
            } else {
                nb = *(const bf16x8*)(pxb + (s + 1) * 32);
            }
        }

        bf16x8 ah, al;
        if (AFP32) {
            float av[8] = {a0.x, a0.y, a0.z, a0.w, a1.x, a1.y, a1.z, a1.w};
            #pragma unroll
            for (int j = 0; j < 8; ++j) {
                unsigned short h = f2bf(av[j]);
                ah[j] = (short)h;
                al[j] = (short)f2bf(av[j] - bf2f(h));
            }
        } else {
            ah = ab;
        }

        const char* base = smem + (s & 1) * 16384 + lane * 16;
        #pragma unroll
        for (int c = 0; c < 8; ++c) {
            bf16x8 bh = *(const bf16x8*)(base + (c * 2) * 1024);
            bf16x8 bl = *(const bf16x8*)(base + (c * 2 + 1) * 1024);
            acc[c] = __builtin_amdgcn_mfma_f32_16x16x32_bf16(ah, bh, acc[c], 0, 0, 0);
            acc[c] = __builtin_amdgcn_mfma_f32_16x16x32_bf16(ah, bl, acc[c], 0, 0, 0);
            if (AFP32)
                acc[c] = __builtin_amdgcn_mfma_f32_16x16x32_bf16(al, bh, acc[c], 0, 0, 0);
        }
        a0 = n0; a1 = n1; ab = nb;
    }

    #pragma unroll
    for (int r = 0; r < 4; ++r) {
        int orow = row0 + lk * 4 + r;
        if (orow >= n) continue;
        float norm = rsqrtf(fmaxf((float)degs[orow], 1.0f));
        #pragma unroll
        for (int c = 0; c < 8; ++c) {
            float v = acc[c][r];
            if (cvec) v += cvec[c * 16 + lr];
            T[(size_t)orow * 128 + c * 16 + lr] = f2bf(v * norm);
        }
    }
}

// ---------------------------------------------------------------- aggregate: padded CSR, zero tail -> always 8 gathers in flight
// T bf16 [(n+1)][128]; row n is all zeros (pad target). Wave = node;
// 2 rows per gather instr (32 lanes x 8B each); plen = ceil(din/16)*16.
template <bool OUT_BF16>
__global__ __launch_bounds__(256) void aggregate(
    const unsigned short* __restrict__ T, const int* __restrict__ prow,
    const int* __restrict__ din, const int* __restrict__ csr,
    const float* __restrict__ bias, void* __restrict__ out_, int n) {
    const int wave = threadIdx.x >> 6;
    const int lane = threadIdx.x & 63;
    const int half = lane >> 5;
    const int l32 = lane & 31;
    const int node = blockIdx.x * 4 + wave;
    if (node >= n) return;
    const int beg = prow[node];
    const int d = din[node];
    const int plen = (d + 15) & ~15;
    float a0 = 0.f, a1 = 0.f, a2 = 0.f, a3 = 0.f;
    for (int e = beg; e < beg + plen; e += 16) {
        int sidx[8];
        #pragma unroll
        for (int j = 0; j < 8; ++j) sidx[j] = csr[e + j * 2 + half];
        #pragma unroll
        for (int j = 0; j < 8; ++j) {
            uint2 u = *(const uint2*)&T[(size_t)sidx[j] * 128 + l32 * 4];
            a0 += __uint_as_float(u.x << 16);
            a1 += __uint_as_float(u.x & 0xffff0000u);
            a2 += __uint_as_float(u.y << 16);
            a3 += __uint_as_float(u.y & 0xffff0000u);
        }
    }
    a0 += __shfl_xor(a0, 32);
    a1 += __shfl_xor(a1, 32);
    a2 += __shfl_xor(a2, 32);
    a3 += __shfl_xor(a3, 32);
    if (half == 0) {
        float norm = rsqrtf(fmaxf((float)d, 1.0f));
        float4 bv = *(const float4*)&bias[l32 * 4];
        float o0 = fmaxf(a0 * norm + bv.x, 0.f);
        float o1 = fmaxf(a1 * norm + bv.y, 0.f);
        float o2 = fmaxf(a2 * norm + bv.z, 0.f);
        float o3 = fmaxf(a3 * norm + bv.w, 0.f);
        if (OUT_BF16) {
            unsigned w0 = (unsigned)f2bf(o0) | ((unsigned)f2bf(o1) << 16);
            unsigned w1 = (unsigned)f2bf(o2) | ((unsigned)f2bf(o3) << 16);
            uint2* dst = (uint2*)((unsigned short*)out_ + (size_t)node * 128 + l32 * 4);
            *dst = make_uint2(w0, w1);
        } else {
            float4* dst = (float4*)((float*)out_ + (size_t)node * 128 + l32 * 4);
            *dst = make_float4(o0, o1, o2, o3);
        }
    }
}

// ---------------------------------------------------------------- launch
extern "C" void kernel_launch(void* const* d_in, const int* in_sizes, int n_in,
                              void* d_out, int out_size, void* d_ws, size_t ws_size,
                              hipStream_t stream) {
    const float* x   = (const float*)d_in[0];
    const float* We  = (const float*)d_in[1];
    const float* be  = (const float*)d_in[2];
    const float* W1  = (const float*)d_in[3];
    const float* b1  = (const float*)d_in[4];
    const float* W2  = (const float*)d_in[5];
    const float* b2  = (const float*)d_in[6];
    const int* src0  = (const int*)d_in[7];
    const int* dst0  = (const int*)d_in[8];
    const int* src1  = (const int*)d_in[9];
    const int* dst1  = (const int*)d_in[10];
    float* out = (float*)d_out;

    const int n = in_sizes[0] / 256;   // 100000
    const int E = in_sizes[7];         // 1600000
    const int chunk = (E + NB - 1) / NB;

    char* p = (char*)d_ws;
    auto carve = [&](size_t bytes) -> void* {
        void* r = (void*)p;
        p += (bytes + 511) & ~(size_t)511;
        return r;
    };
    unsigned short* t        = (unsigned short*)carve(((size_t)n + 1) * HID * 2);  // [(n+1)][128] bf16, row n = zeros
    unsigned*       bucketed = (unsigned*)carve((size_t)4 * E * 4);                // dead after finalize -> h1 overlay
    int*            counts   = (int*)carve((size_t)M4 * 4);
    int*            partials = (int*)carve(1024 * 4);
    int*            csr0     = (int*)carve((size_t)NBUCK * PCAP * 4);   // 14.7 MB
    int*            csr1     = (int*)carve((size_t)NBUCK * PCAP * 4);
    int*            prow0    = (int*)carve((size_t)n * 4);
    int*            prow1    = (int*)carve((size_t)n * 4);
    int*            din0     = (int*)carve((size_t)n * 4);
    int*            din1     = (int*)carve((size_t)n * 4);
    int*            dout0    = (int*)carve((size_t)n * 4);
    int*            dout1    = (int*)carve((size_t)n * 4);
    unsigned short* B1h      = (unsigned short*)carve(256 * HID * 2);
    unsigned short* B1l      = (unsigned short*)carve(256 * HID * 2);
    unsigned short* B2h      = (unsigned short*)carve(128 * HID * 2);
    unsigned short* B2l      = (unsigned short*)carve(128 * HID * 2);
    float*          cv       = (float*)carve(HID * 4);

    unsigned short* h1 = (unsigned short*)bucketed;   // bucketed dead after finalize; exact 25.6 MB fit

    const int gGemm  = (n + 127) / 128;      // 782 blocks, 8 waves
    const int gAggN  = (n + 3) / 4;
    const int gScanA = (M4 + 1023) / 1024;
    const int gScanC = (M4 + 255) / 256;

    // zero pad-row of t (gathers for padded csr entries land here, stays L2-hot)
    hipMemsetAsync(t + (size_t)n * HID, 0, HID * 2, stream);

    // --- graph build (zero global atomics) ---
    bucket_count_all<<<NB, 256, 0, stream>>>(dst0, dst1, src0, src1, counts, E, chunk);
    scan_a<<<gScanA, 256, 0, stream>>>(counts, partials, M4);
    scan_b<<<1, 1024, 0, stream>>>(partials, gScanA);
    scan_c<<<gScanC, 256, 0, stream>>>(counts, partials, M4);
    bucket_scatter_all<<<NB, 256, 0, stream>>>(dst0, dst1, src0, src1, src0, src1,
                                               counts, bucketed, E, chunk);
    bucket_finalize<<<4 * NBUCK, 256, 0, stream>>>(bucketed, counts, prow0, prow1,
                                                   din0, din1, dout0, dout1, csr0, csr1, n, E);

    // --- weights ---
    weight_fuse<<<129, 256, 0, stream>>>(We, be, W1, B1h, B1l, cv);
    swizzle_split<<<(128 * 128 + 255) / 256, 256, 0, stream>>>(W2, B2h, B2l, 128);

    // --- network ---
    gemm_lds<256, true><<<gGemm, 512, 0, stream>>>((const void*)x, B1h, B1l, cv, dout0, t, n);
    aggregate<true><<<gAggN, 256, 0, stream>>>(t, prow0, din0, csr0, b1, (void*)h1, n);
    gemm_lds<128, false><<<gGemm, 512, 0, stream>>>((const void*)h1, B2h, B2l, nullptr, dout1, t, n);
    aggregate<false><<<gAggN, 256, 0, stream>>>(t, prow1, din1, csr1, b2, (void*)out, n);
}